// Round 4
// baseline (498.365 us; speedup 1.0000x reference)
//
#include <hip/hip_runtime.h>
#include <hip/hip_fp16.h>
#include <stdint.h>

// InstantNGP hash-grid embedding, round 4.
// Bottleneck (round 3): L1/TA line-lookup rate ~1/cy/CU; 134M lane-gathers.
// Attack: wider dense entries so one lookup fetches multiple corners.
//   levels 0-6 : quad (x,y neighbors dup, 16B)  -> 2 lookups/pt
//   levels 7-8 : pair (x neighbor dup, 8B)      -> 4 lookups/pt
//   levels 9-15: fp16 hash table (2MB, L2-res)  -> 8 lookups/pt
// ~79 lookups/pt vs 134. Level-phased grid (blockIdx.y) keeps the active
// table L2-resident. tmp half2 level-major + tiled transpose as round 3.

#define N_LEVELS   16
#define LOG2_T     19
#define TABLE_SIZE (1u << LOG2_T)
#define HASH_MASK  (TABLE_SIZE - 1u)
#define P1 2654435761u
#define P2 805459861u

__constant__ int   c_res[N_LEVELS]   = {16, 20, 25, 32, 40, 50, 64, 80,
                                        101, 128, 161, 203, 256, 322, 406, 512};
// scale = res/2 (exact fp32); rel=(x+1)*scale matches ref to <=1 ulp.
__constant__ float c_scale[N_LEVELS] = {8.0f, 10.0f, 12.5f, 16.0f, 20.0f, 25.0f,
                                        32.0f, 40.0f, 50.5f, 64.0f, 80.5f, 101.5f,
                                        128.0f, 161.0f, 203.0f, 256.0f};

enum { M_SCALAR = 0, M_PAIR = 1, M_QUAD = 2, M_HASH = 3 };

struct LevelDesc { uint32_t mode, byteoff, dimx, dimy, nent; };
struct Plan { LevelDesc d[N_LEVELS]; };

// ---------------- pass 0: build per-level staged tables --------------------
__global__ __launch_bounds__(256) void conv_all(
    const float2* __restrict__ emb, char* __restrict__ ws, Plan plan)
{
    const int l = blockIdx.y;
    const LevelDesc D = plan.d[l];
    uint32_t e = blockIdx.x * 256u + threadIdx.x;
    if (e >= D.nent) return;

    const float2* __restrict__ tb = emb + (size_t)l * TABLE_SIZE;

    if (D.mode == M_HASH) {                   // straight fp32->fp16 convert
        __half2 h = __float22half2_rn(tb[e]);
        ((uint32_t*)(ws + D.byteoff))[e] = *(uint32_t*)&h;
        return;
    }

    uint32_t ix = e % D.dimx;
    uint32_t t  = e / D.dimx;
    uint32_t iy = t % D.dimy;
    uint32_t iz = t / D.dimy;
    uint32_t hy = iy * P1, hz = iz * P2;

    if (D.mode == M_QUAD) {
        uint32_t h00 = (ix        ^ hy        ^ hz) & HASH_MASK;
        uint32_t h10 = ((ix + 1u) ^ hy        ^ hz) & HASH_MASK;
        uint32_t h01 = (ix        ^ (hy + P1) ^ hz) & HASH_MASK;
        uint32_t h11 = ((ix + 1u) ^ (hy + P1) ^ hz) & HASH_MASK;
        __half2 a = __float22half2_rn(tb[h00]);
        __half2 b = __float22half2_rn(tb[h10]);
        __half2 c = __float22half2_rn(tb[h01]);
        __half2 d = __float22half2_rn(tb[h11]);
        ((uint4*)(ws + D.byteoff))[e] =
            make_uint4(*(uint32_t*)&a, *(uint32_t*)&b, *(uint32_t*)&c, *(uint32_t*)&d);
    } else if (D.mode == M_PAIR) {
        uint32_t h0 = (ix        ^ hy ^ hz) & HASH_MASK;
        uint32_t h1 = ((ix + 1u) ^ hy ^ hz) & HASH_MASK;
        __half2 a = __float22half2_rn(tb[h0]);
        __half2 b = __float22half2_rn(tb[h1]);
        ((uint2*)(ws + D.byteoff))[e] = make_uint2(*(uint32_t*)&a, *(uint32_t*)&b);
    } else {                                  // M_SCALAR
        uint32_t h0 = (ix ^ hy ^ hz) & HASH_MASK;
        __half2 a = __float22half2_rn(tb[h0]);
        ((uint32_t*)(ws + D.byteoff))[e] = *(uint32_t*)&a;
    }
}

// ---------------- pass 1: level-phased gather ------------------------------
__device__ __forceinline__ void do_point(
    const LevelDesc& D, int l, int b, int npts,
    const float* __restrict__ x, const char* __restrict__ ws,
    uint32_t* __restrict__ tmp)
{
    if (b >= npts) return;
    size_t xb = (size_t)b * 3;
    float xx = x[xb], xy = x[xb + 1], xz = x[xb + 2];

    float scale = c_scale[l];
    float hi    = (float)c_res[l] - 1.0f;

    float rx = (xx + 1.0f) * scale;
    float ry = (xy + 1.0f) * scale;
    float rz = (xz + 1.0f) * scale;

    float fx = fminf(fmaxf(floorf(rx), 0.0f), hi);
    float fy = fminf(fmaxf(floorf(ry), 0.0f), hi);
    float fz = fminf(fmaxf(floorf(rz), 0.0f), hi);

    float wx = rx - fx, wy = ry - fy, wz = rz - fz;
    uint32_t ix = (uint32_t)fx, iy = (uint32_t)fy, iz = (uint32_t)fz;

    // u{x}{y}{z}
    uint32_t u000, u100, u010, u110, u001, u101, u011, u111;

    if (D.mode == M_HASH) {
        const uint32_t* __restrict__ tb = (const uint32_t*)(ws + D.byteoff);
        uint32_t a0 = ix,      a1 = ix + 1u;
        uint32_t b0 = iy * P1, b1 = b0 + P1;
        uint32_t c0 = iz * P2, c1 = c0 + P2;
        u000 = tb[(a0 ^ b0 ^ c0) & HASH_MASK];
        u100 = tb[(a1 ^ b0 ^ c0) & HASH_MASK];
        u010 = tb[(a0 ^ b1 ^ c0) & HASH_MASK];
        u110 = tb[(a1 ^ b1 ^ c0) & HASH_MASK];
        u001 = tb[(a0 ^ b0 ^ c1) & HASH_MASK];
        u101 = tb[(a1 ^ b0 ^ c1) & HASH_MASK];
        u011 = tb[(a0 ^ b1 ^ c1) & HASH_MASK];
        u111 = tb[(a1 ^ b1 ^ c1) & HASH_MASK];
    } else if (D.mode == M_QUAD) {
        const uint4* __restrict__ g = (const uint4*)(ws + D.byteoff);
        uint32_t idx = (iz * D.dimy + iy) * D.dimx + ix;
        uint4 qa = g[idx];                    // z = iz   : {v00,v10,v01,v11}
        uint4 qb = g[idx + D.dimx * D.dimy];  // z = iz+1
        u000 = qa.x; u100 = qa.y; u010 = qa.z; u110 = qa.w;
        u001 = qb.x; u101 = qb.y; u011 = qb.z; u111 = qb.w;
    } else if (D.mode == M_PAIR) {
        const uint2* __restrict__ g = (const uint2*)(ws + D.byteoff);
        uint32_t sxy = D.dimx * D.dimy;
        uint32_t idx = (iz * D.dimy + iy) * D.dimx + ix;
        uint2 a = g[idx];
        uint2 b2 = g[idx + D.dimx];
        uint2 c = g[idx + sxy];
        uint2 d = g[idx + sxy + D.dimx];
        u000 = a.x;  u100 = a.y;
        u010 = b2.x; u110 = b2.y;
        u001 = c.x;  u101 = c.y;
        u011 = d.x;  u111 = d.y;
    } else {                                  // M_SCALAR (fallback config)
        const uint32_t* __restrict__ g = (const uint32_t*)(ws + D.byteoff);
        uint32_t sxy = D.dimx * D.dimy;
        uint32_t idx = (iz * D.dimy + iy) * D.dimx + ix;
        u000 = g[idx];               u100 = g[idx + 1];
        u010 = g[idx + D.dimx];      u110 = g[idx + D.dimx + 1];
        u001 = g[idx + sxy];         u101 = g[idx + sxy + 1];
        u011 = g[idx + sxy + D.dimx]; u111 = g[idx + sxy + D.dimx + 1];
    }

    float2 v000 = __half22float2(*(__half2*)&u000);
    float2 v100 = __half22float2(*(__half2*)&u100);
    float2 v010 = __half22float2(*(__half2*)&u010);
    float2 v110 = __half22float2(*(__half2*)&u110);
    float2 v001 = __half22float2(*(__half2*)&u001);
    float2 v101 = __half22float2(*(__half2*)&u101);
    float2 v011 = __half22float2(*(__half2*)&u011);
    float2 v111 = __half22float2(*(__half2*)&u111);

    float ux = 1.0f - wx, uy = 1.0f - wy, uz = 1.0f - wz;
    float w0 = ux * uy * uz, w1 = wx * uy * uz;
    float w2 = ux * wy * uz, w3 = wx * wy * uz;
    float w4 = ux * uy * wz, w5 = wx * uy * wz;
    float w6 = ux * wy * wz, w7 = wx * wy * wz;

    float o0 = w0 * v000.x + w1 * v100.x + w2 * v010.x + w3 * v110.x
             + w4 * v001.x + w5 * v101.x + w6 * v011.x + w7 * v111.x;
    float o1 = w0 * v000.y + w1 * v100.y + w2 * v010.y + w3 * v110.y
             + w4 * v001.y + w5 * v101.y + w6 * v011.y + w7 * v111.y;

    __half2 r = __float22half2_rn(make_float2(o0, o1));
    tmp[(size_t)l * npts + b] = *(uint32_t*)&r;
}

__global__ __launch_bounds__(256) void gather_lvl(
    const float* __restrict__ x, const char* __restrict__ ws,
    uint32_t* __restrict__ tmp, int npts, Plan plan)
{
    const int l = blockIdx.y;
    const LevelDesc D = plan.d[l];
    const int bA = blockIdx.x * 512 + threadIdx.x;
    do_point(D, l, bA,       npts, x, ws, tmp);
    do_point(D, l, bA + 256, npts, x, ws, tmp);
}

// ---------------- pass 2: tmp[l][b] (half2) -> out[b][l] (float2) ----------
__global__ __launch_bounds__(256) void transpose_k(
    const uint32_t* __restrict__ tmp, float4* __restrict__ out4, int npts)
{
    __shared__ uint32_t sm[N_LEVELS][514];    // pad 2 -> <=2-way conflicts

    const int b0 = blockIdx.x * 512;
    const int t  = threadIdx.x;

    if (b0 + 512 <= npts) {
        #pragma unroll
        for (int l = 0; l < N_LEVELS; ++l) {
            uint2 u = *(const uint2*)&tmp[(size_t)l * npts + b0 + 2 * t];
            sm[l][2 * t]     = u.x;
            sm[l][2 * t + 1] = u.y;
        }
        __syncthreads();
        #pragma unroll
        for (int k = 0; k < 16; ++k) {
            int q = k * 256 + t;
            int p = q >> 3;
            int j = q & 7;
            uint32_t a = sm[2 * j][p], b = sm[2 * j + 1][p];
            float2 f0 = __half22float2(*(__half2*)&a);
            float2 f1 = __half22float2(*(__half2*)&b);
            out4[(size_t)(b0 + p) * 8 + j] = make_float4(f0.x, f0.y, f1.x, f1.y);
        }
    } else {
        for (int l = 0; l < N_LEVELS; ++l) {
            for (int s = 0; s < 2; ++s) {
                int b = b0 + 2 * t + s;
                if (b < npts) sm[l][2 * t + s] = tmp[(size_t)l * npts + b];
            }
        }
        __syncthreads();
        for (int k = 0; k < 16; ++k) {
            int q = k * 256 + t;
            int p = q >> 3, j = q & 7;
            if (b0 + p < npts) {
                uint32_t a = sm[2 * j][p], b = sm[2 * j + 1][p];
                float2 f0 = __half22float2(*(__half2*)&a);
                float2 f1 = __half22float2(*(__half2*)&b);
                out4[(size_t)(b0 + p) * 8 + j] = make_float4(f0.x, f0.y, f1.x, f1.y);
            }
        }
    }
}

// ---------------- fallback (no workspace): direct fp32, point-major --------
__global__ __launch_bounds__(256) void hash_embed_direct(
    const float* __restrict__ x, const float* __restrict__ emb,
    float2* __restrict__ out, int npts)
{
    int t = blockIdx.x * 256 + threadIdx.x;
    int l = t & 15, b = t >> 4;
    if (b >= npts) return;
    size_t xb = (size_t)b * 3;
    float scale = c_scale[l], hi = (float)c_res[l] - 1.0f;
    float rx = (x[xb] + 1.0f) * scale, ry = (x[xb+1] + 1.0f) * scale, rz = (x[xb+2] + 1.0f) * scale;
    float fx = fminf(fmaxf(floorf(rx), 0.0f), hi);
    float fy = fminf(fmaxf(floorf(ry), 0.0f), hi);
    float fz = fminf(fmaxf(floorf(rz), 0.0f), hi);
    float wx = rx - fx, wy = ry - fy, wz = rz - fz;
    uint32_t ix = (uint32_t)fx, iy = (uint32_t)fy, iz = (uint32_t)fz;
    uint32_t a0 = ix, a1 = ix + 1u, b0 = iy * P1, b1 = b0 + P1, c0 = iz * P2, c1 = c0 + P2;
    const float2* tb = (const float2*)emb + (size_t)l * TABLE_SIZE;
    float2 v0 = tb[(a0^b0^c0)&HASH_MASK], v1 = tb[(a1^b0^c0)&HASH_MASK];
    float2 v2 = tb[(a0^b1^c0)&HASH_MASK], v3 = tb[(a1^b1^c0)&HASH_MASK];
    float2 v4 = tb[(a0^b0^c1)&HASH_MASK], v5 = tb[(a1^b0^c1)&HASH_MASK];
    float2 v6 = tb[(a0^b1^c1)&HASH_MASK], v7 = tb[(a1^b1^c1)&HASH_MASK];
    float ux = 1.0f - wx, uy = 1.0f - wy, uz = 1.0f - wz;
    float w0 = ux*uy*uz, w1 = wx*uy*uz, w2 = ux*wy*uz, w3 = wx*wy*uz;
    float w4 = ux*uy*wz, w5 = wx*uy*wz, w6 = ux*wy*wz, w7 = wx*wy*wz;
    float o0 = w0*v0.x+w1*v1.x+w2*v2.x+w3*v3.x+w4*v4.x+w5*v5.x+w6*v6.x+w7*v7.x;
    float o1 = w0*v0.y+w1*v1.y+w2*v2.y+w3*v3.y+w4*v4.y+w5*v5.y+w6*v6.y+w7*v7.y;
    out[(size_t)b * N_LEVELS + l] = make_float2(o0, o1);
}

// ---------------- host ------------------------------------------------------
static void add_dense(Plan& plan, int l, uint32_t mode, size_t& off, int R)
{
    uint32_t dimx, dimy, dimz, esize;
    if (mode == M_QUAD)      { dimx = R;     dimy = R;     dimz = R + 1; esize = 16; }
    else if (mode == M_PAIR) { dimx = R;     dimy = R + 1; dimz = R + 1; esize = 8;  }
    else                     { dimx = R + 1; dimy = R + 1; dimz = R + 1; esize = 4;  }
    uint32_t nent = dimx * dimy * dimz;
    plan.d[l] = { mode, (uint32_t)off, dimx, dimy, nent };
    off += (size_t)nent * esize;
}

static void add_hash(Plan& plan, int l, size_t& off)
{
    plan.d[l] = { M_HASH, (uint32_t)off, 0, 0, TABLE_SIZE };
    off += (size_t)TABLE_SIZE * 4;
}

extern "C" void kernel_launch(void* const* d_in, const int* in_sizes, int n_in,
                              void* d_out, int out_size, void* d_ws, size_t ws_size,
                              hipStream_t stream)
{
    static const int h_res[N_LEVELS] = {16, 20, 25, 32, 40, 50, 64, 80,
                                        101, 128, 161, 203, 256, 322, 406, 512};
    const float*  x   = (const float*)d_in[0];
    const float2* emb = (const float2*)d_in[1];
    int npts = in_sizes[0] / 3;

    size_t tmp_bytes = (size_t)npts * N_LEVELS * 4;   // half2 per (pt,lvl)

    // Config FULL: quad l0-6, pair l7-8, hash l9-15  (~102.7 MB)
    Plan full; size_t off_full = tmp_bytes;
    for (int l = 0; l <= 6; ++l)  add_dense(full, l, M_QUAD, off_full, h_res[l]);
    for (int l = 7; l <= 8; ++l)  add_dense(full, l, M_PAIR, off_full, h_res[l]);
    for (int l = 9; l < 16; ++l)  add_hash(full, l, off_full);

    // Config SMALL (round-3 equivalent): scalar l0-7, hash l8-15 (~88.2 MB)
    Plan small; size_t off_small = tmp_bytes;
    for (int l = 0; l <= 7; ++l)  add_dense(small, l, M_SCALAR, off_small, h_res[l]);
    for (int l = 8; l < 16; ++l)  add_hash(small, l, off_small);

    const Plan* plan = nullptr;
    if (ws_size >= off_full)       plan = &full;
    else if (ws_size >= off_small) plan = &small;

    if (plan) {
        uint32_t maxent = 0;
        for (int l = 0; l < 16; ++l) maxent = max(maxent, plan->d[l].nent);

        hipLaunchKernelGGL(conv_all,
                           dim3((maxent + 255) / 256, N_LEVELS), dim3(256), 0, stream,
                           emb, (char*)d_ws, *plan);
        hipLaunchKernelGGL(gather_lvl,
                           dim3((npts + 511) / 512, N_LEVELS), dim3(256), 0, stream,
                           x, (const char*)d_ws, (uint32_t*)d_ws, npts, *plan);
        hipLaunchKernelGGL(transpose_k,
                           dim3((npts + 511) / 512), dim3(256), 0, stream,
                           (const uint32_t*)d_ws, (float4*)d_out, npts);
    } else {
        int total = npts * N_LEVELS;
        hipLaunchKernelGGL(hash_embed_direct,
                           dim3((total + 255) / 256), dim3(256), 0, stream,
                           x, (const float*)emb, (float2*)d_out, npts);
    }
}